// Round 12
// baseline (370.728 us; speedup 1.0000x reference)
//
#include <hip/hip_runtime.h>
#include <cstdint>
#include <cstddef>

#define NN 50000
#define NE 600000
#define FIN 64
#define HID 128
#define NCLS 10
#define NLAYER 3

// 0.25 (1/sqrt(16)) * log2(e)  -> softmax exp becomes a single exp2
#define QSCALE 0.36067376022224085f

typedef __bf16 bf16x8 __attribute__((ext_vector_type(8)));
typedef float f32x4 __attribute__((ext_vector_type(4)));
typedef float f32x2 __attribute__((ext_vector_type(2)));

__device__ __forceinline__ unsigned short f2bf(float f) {
    unsigned int u = __builtin_bit_cast(unsigned int, f);
    u += 0x7fffu + ((u >> 16) & 1u);
    return (unsigned short)(u >> 16);
}
__device__ __forceinline__ float bf2f(unsigned short s) {
    unsigned int u = ((unsigned int)s) << 16;
    return __builtin_bit_cast(float, u);
}
__device__ __forceinline__ uint2 nt_load8(const void* p) {
    unsigned long long r = __builtin_nontemporal_load((const unsigned long long*)p);
    return __builtin_bit_cast(uint2, r);
}

// ---------------------------------------------------------------- prep: weights + count
__global__ __launch_bounds__(256) void k_prep(
    const float* __restrict__ Wq, const float* __restrict__ Wk,
    const float* __restrict__ Wv, const float* __restrict__ Ws,
    const float* __restrict__ Wbe, const float* __restrict__ Waf,
    unsigned short* __restrict__ Wt12,
    unsigned short* __restrict__ Wbt,
    float* __restrict__ Wat,
    const int* __restrict__ edst, int* __restrict__ counts)
{
    int blk = blockIdx.x;
    int tid = threadIdx.x;
    if (blk < 768) {
        int m = blk >> 6;                 // 0..11
        int l = m >> 2, which = m & 3;
        const float* src;
        if (which == 0) src = Wq; else if (which == 1) src = Wk;
        else if (which == 2) src = Wv; else src = Ws;
        src += (size_t)l * HID * HID;
        int idx = (blk & 63) * 256 + tid; // 0..16383
        int c = idx >> 7, k = idx & 127;
        Wt12[(size_t)m * 16384 + (size_t)c * 128 + k] = f2bf(src[(size_t)k * 128 + c]);
    } else if (blk < 800) {
        int idx = (blk - 768) * 256 + tid;  // 0..8191
        int c = idx >> 6, k = idx & 63;
        Wbt[(size_t)c * 64 + k] = f2bf(Wbe[(size_t)k * 128 + c]);
    } else if (blk < 805) {
        int i = (blk - 800) * 256 + tid;    // 0..1279
        if (i < 1280) {
            int c = i >> 7, f = i & 127;
            Wat[i] = Waf[f * 10 + c];
        }
    } else {
        int e = (blk - 805) * 256 + tid;
        if (e < NE) atomicAdd(&counts[edst[e]], 1);
    }
}

// ---------------------------------------------------------------- CSR scan (2-kernel)
__global__ __launch_bounds__(512) void k_scan1(const int* __restrict__ counts,
                                               int* __restrict__ row_ptr,
                                               int* __restrict__ partials, int n) {
    __shared__ int sm[512];
    int tid = threadIdx.x;
    int i = blockIdx.x * 512 + tid;
    int v = (i < n) ? counts[i] : 0;
    sm[tid] = v;
    __syncthreads();
    #pragma unroll
    for (int off = 1; off < 512; off <<= 1) {
        int t = (tid >= off) ? sm[tid - off] : 0;
        __syncthreads();
        sm[tid] += t;
        __syncthreads();
    }
    if (i < n) row_ptr[i] = sm[tid] - v;
    if (tid == 511) partials[blockIdx.x] = sm[511];
}

// scan3 with the partials scan folded in (each block redundantly scans <=128 partials)
__global__ __launch_bounds__(512) void k_scan3(int* __restrict__ row_ptr,
                                               const int* __restrict__ partials,
                                               int n, int nb) {
    __shared__ int sp[128];
    const int tid = threadIdx.x;
    if (tid < 128) sp[tid] = (tid < nb) ? partials[tid] : 0;
    __syncthreads();
    #pragma unroll
    for (int off = 1; off < 128; off <<= 1) {
        int t = 0;
        if (tid < 128 && tid >= off) t = sp[tid - off];
        __syncthreads();
        if (tid < 128) sp[tid] += t;
        __syncthreads();
    }
    const int add = (blockIdx.x == 0) ? 0 : sp[blockIdx.x - 1];
    const int i = blockIdx.x * 512 + tid;
    if (i < n) row_ptr[i] += add;
}

// fill: atomicAdd directly on row_ptr. Afterwards row_ptr[d] = orig_row_ptr[d+1],
// so consumers read beg = row_ptr[n-1] (row_ptr[-1] is a zeroed sentinel).
__global__ __launch_bounds__(256) void k_fill(const int* __restrict__ esrc,
                                              const int* __restrict__ edst,
                                              const float* __restrict__ dist,
                                              int* __restrict__ row_ptr,
                                              int2* __restrict__ srcd) {
    int e = blockIdx.x * 256 + threadIdx.x;
    if (e < NE) {
        int d = edst[e];
        int slot = atomicAdd(&row_ptr[d], 1);
        srcd[slot] = make_int2(esrc[e], __float_as_int(dist[e]));
    }
}

// ---------------------------------------------------------------- QKVS core
// kv8 row layout: 32 chunks of 8B, chunk c = [k(4c..4c+3) 4B | v(4c..4c+3) 4B] fp8.
__device__ __forceinline__ void qkvs_store(
    int m, int arow, int colb, f32x4 acc, float4 bb, int nrows,
    unsigned short* __restrict__ qb, unsigned char* __restrict__ kv8,
    unsigned short* __restrict__ hsb)
{
    if (arow >= nrows) return;
    float v0 = acc[0] + bb.x, v1 = acc[1] + bb.y;
    float v2 = acc[2] + bb.z, v3 = acc[3] + bb.w;
    if (m == 0) {
        ushort4 o;
        o.x = f2bf(v0 * QSCALE); o.y = f2bf(v1 * QSCALE);
        o.z = f2bf(v2 * QSCALE); o.w = f2bf(v3 * QSCALE);
        *(ushort4*)(qb + (size_t)arow * 128 + colb) = o;
    } else if (m == 1 || m == 2) {
        unsigned int pk = __builtin_amdgcn_cvt_pk_fp8_f32(v0, v1, 0, false);
        pk = __builtin_amdgcn_cvt_pk_fp8_f32(v2, v3, pk, true);
        *(unsigned int*)(kv8 + (size_t)arow * 256 + (colb >> 2) * 8 + (m == 2 ? 4 : 0)) = pk;
    } else {
        ushort4 o;
        o.x = f2bf(v0); o.y = f2bf(v1); o.z = f2bf(v2); o.w = f2bf(v3);
        *(ushort4*)(hsb + (size_t)arow * 128 + colb) = o;
    }
}

// ---------------------------------------------------------------- fused QKVS GEMM (layers 1,2)
__global__ __launch_bounds__(512) void k_qkvs(
    const unsigned short* __restrict__ Ab, int nrows,
    const unsigned short* __restrict__ Wt,   // [4][128col][128k]
    const float* __restrict__ bq, const float* __restrict__ bk,
    const float* __restrict__ bv, const float* __restrict__ bs,
    unsigned short* __restrict__ qb,
    unsigned char* __restrict__ kv8,
    unsigned short* __restrict__ hsb)
{
    const int tid = threadIdx.x;
    const int w = tid >> 6, lane = tid & 63;
    const int m = w >> 1, ch = w & 1;
    const float* bias = (m == 0) ? bq : (m == 1) ? bk : (m == 2) ? bv : bs;
    const unsigned short* Wm = Wt + (size_t)m * 16384;
    const int lc = lane & 15, lk = lane >> 4;

    bf16x8 bw[4][4];
    float4 bb[4];
    #pragma unroll
    for (int ct = 0; ct < 4; ++ct) {
        int col = ch * 64 + ct * 16 + lc;
        bb[ct] = *(const float4*)(bias + ch * 64 + ct * 16 + lk * 4);
        #pragma unroll
        for (int kb = 0; kb < 4; ++kb)
            bw[ct][kb] = *(const bf16x8*)(Wm + (size_t)col * 128 + kb * 32 + lk * 8);
    }

    const int r0 = blockIdx.x * 64;
    #pragma unroll
    for (int rt = 0; rt < 4; ++rt) {
        const int arow = r0 + rt * 16 + lc;
        const bool rv = arow < nrows;
        bf16x8 z = {};
        bf16x8 a[4];
        #pragma unroll
        for (int kb = 0; kb < 4; ++kb)
            a[kb] = rv ? *(const bf16x8*)(Ab + (size_t)arow * 128 + kb * 32 + lk * 8) : z;
        #pragma unroll
        for (int ct = 0; ct < 4; ++ct) {
            f32x4 acc = {0.f, 0.f, 0.f, 0.f};
            #pragma unroll
            for (int kb = 0; kb < 4; ++kb)
                acc = __builtin_amdgcn_mfma_f32_16x16x32_bf16(bw[ct][kb], a[kb], acc, 0, 0, 0);
            qkvs_store(m, arow, ch * 64 + ct * 16 + lk * 4, acc, bb[ct], nrows, qb, kv8, hsb);
        }
    }
}

// ---------------------------------------------------------------- fused fc_before + layer0 QKVS
__global__ __launch_bounds__(512) void k_gqkvs(
    const float* __restrict__ x, int nrows,
    const unsigned short* __restrict__ Wbt,  // [128col][64k]
    const float* __restrict__ bbe,
    const unsigned short* __restrict__ Wt,   // layer0 [4][128col][128k]
    const float* __restrict__ bq, const float* __restrict__ bk,
    const float* __restrict__ bv, const float* __restrict__ bs,
    unsigned short* __restrict__ qb,
    unsigned char* __restrict__ kv8,
    unsigned short* __restrict__ hsb)
{
    __shared__ unsigned short hs_s[64 * 136];   // stride 136 shorts (272B) -> 2-way only
    const int tid = threadIdx.x;
    const int w = tid >> 6, lane = tid & 63;
    const int lc = lane & 15, lk = lane >> 4;
    const int r0 = blockIdx.x * 64;

    // ---- phase 1: wave w -> row-tile (w&3), col-half (w>>2)
    {
        const int rt0 = w & 3, ch0 = w >> 2;
        const int arl = rt0 * 16 + lc;
        const int arow = r0 + arl;
        const bool rv = arow < nrows;
        bf16x8 a[2];
        #pragma unroll
        for (int kb = 0; kb < 2; ++kb) {
            union { bf16x8 v; unsigned short u[8]; } t;
            #pragma unroll
            for (int q = 0; q < 2; ++q) {
                float4 f = rv ? *(const float4*)(x + (size_t)arow * 64 + kb * 32 + lk * 8 + q * 4)
                              : make_float4(0.f, 0.f, 0.f, 0.f);
                t.u[q * 4 + 0] = f2bf(f.x); t.u[q * 4 + 1] = f2bf(f.y);
                t.u[q * 4 + 2] = f2bf(f.z); t.u[q * 4 + 3] = f2bf(f.w);
            }
            a[kb] = t.v;
        }
        #pragma unroll
        for (int ct = 0; ct < 4; ++ct) {
            const int col = ch0 * 64 + ct * 16 + lc;
            f32x4 acc = {0.f, 0.f, 0.f, 0.f};
            #pragma unroll
            for (int kb = 0; kb < 2; ++kb) {
                bf16x8 bwf = *(const bf16x8*)(Wbt + (size_t)col * 64 + kb * 32 + lk * 8);
                acc = __builtin_amdgcn_mfma_f32_16x16x32_bf16(bwf, a[kb], acc, 0, 0, 0);
            }
            float4 bv_ = *(const float4*)(bbe + ch0 * 64 + ct * 16 + lk * 4);
            ushort4 o;
            o.x = rv ? f2bf(fmaxf(acc[0] + bv_.x, 0.f)) : 0;
            o.y = rv ? f2bf(fmaxf(acc[1] + bv_.y, 0.f)) : 0;
            o.z = rv ? f2bf(fmaxf(acc[2] + bv_.z, 0.f)) : 0;
            o.w = rv ? f2bf(fmaxf(acc[3] + bv_.w, 0.f)) : 0;
            *(ushort4*)(hs_s + arl * 136 + ch0 * 64 + ct * 16 + lk * 4) = o;
        }
    }
    __syncthreads();

    // ---- phase 2: standard QKVS, A from LDS
    const int m = w >> 1, ch = w & 1;
    const float* bias = (m == 0) ? bq : (m == 1) ? bk : (m == 2) ? bv : bs;
    const unsigned short* Wm = Wt + (size_t)m * 16384;

    bf16x8 bw[4][4];
    float4 bb[4];
    #pragma unroll
    for (int ct = 0; ct < 4; ++ct) {
        int col = ch * 64 + ct * 16 + lc;
        bb[ct] = *(const float4*)(bias + ch * 64 + ct * 16 + lk * 4);
        #pragma unroll
        for (int kb = 0; kb < 4; ++kb)
            bw[ct][kb] = *(const bf16x8*)(Wm + (size_t)col * 128 + kb * 32 + lk * 8);
    }

    #pragma unroll
    for (int rt = 0; rt < 4; ++rt) {
        const int arl = rt * 16 + lc;
        const int arow = r0 + arl;
        bf16x8 a[4];
        #pragma unroll
        for (int kb = 0; kb < 4; ++kb)
            a[kb] = *(const bf16x8*)(hs_s + arl * 136 + kb * 32 + lk * 8);
        #pragma unroll
        for (int ct = 0; ct < 4; ++ct) {
            f32x4 acc = {0.f, 0.f, 0.f, 0.f};
            #pragma unroll
            for (int kb = 0; kb < 4; ++kb)
                acc = __builtin_amdgcn_mfma_f32_16x16x32_bf16(bw[ct][kb], a[kb], acc, 0, 0, 0);
            qkvs_store(m, arow, ch * 64 + ct * 16 + lk * 4, acc, bb[ct], nrows, qb, kv8, hsb);
        }
    }
}

// ---------------------------------------------------------------- fused attention (r8 structure + nt loads)
// One wave per dst node. lane = (half = lane>>5 edge parity, l5 = lane&31
// owning dims 4*l5..4*l5+3). Edge list (<=64) loaded in ONE coalesced wave
// load; per chunk of 16 edges: 8 kv gathers burst-issued, then 8 computes.
// row_ptr here is the post-fill array: beg = row_ptr[n-1], end = row_ptr[n].
#define FET(Ki, i) {                                                      \
    int e_ = base + 2 * (i) + half;                                       \
    int ec_ = e_ < cmax ? e_ : 0;                                         \
    int sx_ = __shfl(sd0.x, ec_);                                         \
    Ki = nt_load8(kv8 + (size_t)sx_ * 256 + l5 * 8); }

#define CMP(Ki, i) {                                                      \
    int e_ = base + 2 * (i) + half;                                       \
    bool val_ = e_ < cmax;                                                \
    int ec_ = val_ ? e_ : 0;                                              \
    float dd_ = __int_as_float(__shfl(sd0.y, ec_));                       \
    f32x2 k01_ = __builtin_amdgcn_cvt_pk_f32_fp8(Ki.x, false);            \
    f32x2 k23_ = __builtin_amdgcn_cvt_pk_f32_fp8(Ki.x, true);             \
    float p_ = q0 * k01_.x + q1 * k01_.y + q2 * k23_.x + q3 * k23_.y;     \
    p_ += __shfl_xor(p_, 1);                                              \
    p_ += __shfl_xor(p_, 2);                                              \
    p_ = fmaf(dd_, qwe, p_);                                              \
    float w_ = val_ ? exp2f(p_) : 0.f;                                    \
    s += w_;                                                              \
    sd = fmaf(dd_, w_, sd);                                               \
    f32x2 v01_ = __builtin_amdgcn_cvt_pk_f32_fp8(Ki.y, false);            \
    f32x2 v23_ = __builtin_amdgcn_cvt_pk_f32_fp8(Ki.y, true);             \
    va0 = fmaf(v01_.x, w_, va0); va1 = fmaf(v01_.y, w_, va1);             \
    va2 = fmaf(v23_.x, w_, va2); va3 = fmaf(v23_.y, w_, va3); }

template <int LAST>
__global__ __launch_bounds__(256, 6) void k_attn(
    const unsigned short* __restrict__ qb,
    const unsigned short* __restrict__ hsb,
    const unsigned char* __restrict__ kv8,
    const int2* __restrict__ srcd,
    const float* __restrict__ We,
    const int* __restrict__ row_ptr,
    const float* __restrict__ lng,
    const float* __restrict__ lnb,
    unsigned short* __restrict__ hb,
    const float* __restrict__ Wat,     // [10][128] (LAST)
    const float* __restrict__ ba,      // [10]      (LAST)
    float* __restrict__ out, int nnodes)
{
    const int wid = threadIdx.x >> 6;
    const int lane = threadIdx.x & 63;
    const int n = blockIdx.x * 4 + wid;
    if (n >= nnodes) return;
    const int half = lane >> 5;
    const int l5 = lane & 31;
    const int d0 = l5 * 4;

    const int beg = row_ptr[n - 1];    // sentinel row_ptr[-1] == 0
    const int cnt = row_ptr[n] - beg;

    // q slice (4 dims, pre-scaled bf16) + We slice (nt: read-once streams)
    ushort4 qu = __builtin_bit_cast(ushort4, nt_load8(qb + (size_t)n * 128 + d0));
    const float q0 = bf2f(qu.x), q1 = bf2f(qu.y), q2 = bf2f(qu.z), q3 = bf2f(qu.w);
    const float4 wv = *(const float4*)(We + d0);
    float qwe = q0 * wv.x + q1 * wv.y + q2 * wv.z + q3 * wv.w;
    qwe += __shfl_xor(qwe, 1);
    qwe += __shfl_xor(qwe, 2);

    float s = 0.f, sd = 0.f;
    float va0 = 0.f, va1 = 0.f, va2 = 0.f, va3 = 0.f;

    if (cnt > 0) {
        // whole edge list (<=64) in one coalesced wave load
        int2 sd0 = __builtin_bit_cast(int2,
            nt_load8(srcd + beg + (lane < cnt ? lane : 0)));
        const int cmax = cnt < 64 ? cnt : 64;
        const int nch = (cmax + 15) >> 4;
        for (int ch = 0; ch < nch; ++ch) {
            const int base = ch << 4;
            uint2 kA, kB, kC, kD, kE, kF, kG, kH;
            FET(kA, 0) FET(kB, 1) FET(kC, 2) FET(kD, 3)
            FET(kE, 4) FET(kF, 5) FET(kG, 6) FET(kH, 7)
            CMP(kA, 0) CMP(kB, 1) CMP(kC, 2) CMP(kD, 3)
            CMP(kE, 4) CMP(kF, 5) CMP(kG, 6) CMP(kH, 7)
        }
        // correctness tail for cnt > 64 (never taken on this graph)
        for (int e = 64 + half; e < cnt; e += 2) {
            int2 sde = srcd[beg + e];
            uint2 kr = *(const uint2*)(kv8 + (size_t)sde.x * 256 + l5 * 8);
            float dd_ = __int_as_float(sde.y);
            f32x2 k01_ = __builtin_amdgcn_cvt_pk_f32_fp8(kr.x, false);
            f32x2 k23_ = __builtin_amdgcn_cvt_pk_f32_fp8(kr.x, true);
            float p_ = q0 * k01_.x + q1 * k01_.y + q2 * k23_.x + q3 * k23_.y;
            p_ += __shfl_xor(p_, 1);
            p_ += __shfl_xor(p_, 2);
            p_ = fmaf(dd_, qwe, p_);
            float w_ = exp2f(p_);
            s += w_;
            sd = fmaf(dd_, w_, sd);
            f32x2 v01_ = __builtin_amdgcn_cvt_pk_f32_fp8(kr.y, false);
            f32x2 v23_ = __builtin_amdgcn_cvt_pk_f32_fp8(kr.y, true);
            va0 = fmaf(v01_.x, w_, va0); va1 = fmaf(v01_.y, w_, va1);
            va2 = fmaf(v23_.x, w_, va2); va3 = fmaf(v23_.y, w_, va3);
        }
    }

    // combine the two edge-parity halves
    s  += __shfl_xor(s, 32);
    sd += __shfl_xor(sd, 32);
    va0 += __shfl_xor(va0, 32);
    va1 += __shfl_xor(va1, 32);
    va2 += __shfl_xor(va2, 32);
    va3 += __shfl_xor(va3, 32);

    const float inv = 1.f / (s + 1e-16f);
    const ushort4 hu = __builtin_bit_cast(ushort4, nt_load8(hsb + (size_t)n * 128 + d0));
    float o0 = fmaf(fmaf(wv.x, sd, va0), inv, bf2f(hu.x));
    float o1 = fmaf(fmaf(wv.y, sd, va1), inv, bf2f(hu.y));
    float o2 = fmaf(fmaf(wv.z, sd, va2), inv, bf2f(hu.z));
    float o3 = fmaf(fmaf(wv.w, sd, va3), inv, bf2f(hu.w));

    // LayerNorm over 128 dims (4 per lane, duplicated across halves) + ReLU
    float tt = o0 + o1 + o2 + o3;
    #pragma unroll
    for (int msk = 1; msk < 32; msk <<= 1) tt += __shfl_xor(tt, msk);
    const float mean = tt * 0.0078125f;
    const float e0 = o0 - mean, e1 = o1 - mean, e2 = o2 - mean, e3 = o3 - mean;
    float vv2 = e0 * e0 + e1 * e1 + e2 * e2 + e3 * e3;
    #pragma unroll
    for (int msk = 1; msk < 32; msk <<= 1) vv2 += __shfl_xor(vv2, msk);
    const float rstd = rsqrtf(vv2 * 0.0078125f + 1e-5f);
    const float4 g4 = *(const float4*)(lng + d0);
    const float4 b4 = *(const float4*)(lnb + d0);
    const float y0 = fmaxf(fmaf(e0 * rstd, g4.x, b4.x), 0.f);
    const float y1 = fmaxf(fmaf(e1 * rstd, g4.y, b4.y), 0.f);
    const float y2 = fmaxf(fmaf(e2 * rstd, g4.z, b4.z), 0.f);
    const float y3 = fmaxf(fmaf(e3 * rstd, g4.w, b4.w), 0.f);

    if (LAST) {
        float lg[NCLS];
        #pragma unroll
        for (int c = 0; c < NCLS; ++c) {
            float4 wa = *(const float4*)(Wat + c * 128 + d0);
            float p = y0 * wa.x + y1 * wa.y + y2 * wa.z + y3 * wa.w;
            #pragma unroll
            for (int msk = 1; msk < 32; msk <<= 1) p += __shfl_xor(p, msk);
            lg[c] = p + ba[c];
        }
        float mx = lg[0];
        #pragma unroll
        for (int c = 1; c < NCLS; ++c) mx = fmaxf(mx, lg[c]);
        float sum = 0.f;
        #pragma unroll
        for (int c = 0; c < NCLS; ++c) sum += __expf(lg[c] - mx);
        float lse = mx + __logf(sum);
        if (lane == 0) {
            #pragma unroll
            for (int c = 0; c < NCLS; ++c) out[(size_t)n * NCLS + c] = lg[c] - lse;
        }
    } else if (lane < 32) {
        ushort4 o;
        o.x = f2bf(y0); o.y = f2bf(y1); o.z = f2bf(y2); o.w = f2bf(y3);
        *(ushort4*)(hb + (size_t)n * 128 + d0) = o;
    }
}

// ---------------------------------------------------------------- launch
extern "C" void kernel_launch(void* const* d_in, const int* in_sizes, int n_in,
                              void* d_out, int out_size, void* d_ws, size_t ws_size,
                              hipStream_t stream)
{
    const float* x    = (const float*)d_in[0];
    const int*   ei   = (const int*)d_in[1];
    const float* dist = (const float*)d_in[2];
    const float* Wq   = (const float*)d_in[3];
    const float* bq   = (const float*)d_in[4];
    const float* Wk   = (const float*)d_in[5];
    const float* bk   = (const float*)d_in[6];
    const float* Wv   = (const float*)d_in[7];
    const float* bv   = (const float*)d_in[8];
    const float* We   = (const float*)d_in[9];
    const float* Wsk  = (const float*)d_in[10];
    const float* bs   = (const float*)d_in[11];
    const float* lng  = (const float*)d_in[12];
    const float* lnb  = (const float*)d_in[13];
    const float* Wbe  = (const float*)d_in[14];
    const float* bbe  = (const float*)d_in[15];
    const float* Waf  = (const float*)d_in[16];
    const float* baf  = (const float*)d_in[17];
    float* out = (float*)d_out;
    const int* esrc = ei;
    const int* edst = ei + NE;

    char* ws = (char*)d_ws;
    size_t off = 0;
    unsigned short* qb  = (unsigned short*)(ws + off); off += 12800000;
    unsigned short* hsb = (unsigned short*)(ws + off); off += 12800000;
    unsigned char*  kv8 = (unsigned char*)(ws + off);  off += 12800000;
    unsigned short* hb  = (unsigned short*)(ws + off); off += 12800000;
    unsigned short* Wt12 = (unsigned short*)(ws + off); off += 393216;
    unsigned short* Wbt  = (unsigned short*)(ws + off); off += 16384;
    float* Wat = (float*)(ws + off);   off += 5120;
    int* counts   = (int*)(ws + off);  off += 200192;   // NN+1 used
    int* row_base = (int*)(ws + off);  off += 200704;   // [0]=sentinel 0, then NN+1 entries
    int* partials = (int*)(ws + off);  off += 512;
    int2* srcd    = (int2*)(ws + off); off += (size_t)NE * 8 + 4096;  // +guard
    int* row_ptr = row_base + 1;

    // zero counts + row_base sentinel in ONE memset (adjacent regions)
    hipMemsetAsync(counts, 0, 200192 + 4, stream);
    // weight prep + dst histogram
    k_prep<<<805 + (NE + 255) / 256, 256, 0, stream>>>(
        Wq, Wk, Wv, Wsk, Wbe, Waf, Wt12, Wbt, Wat, edst, counts);
    int nsb = (NN + 1 + 511) / 512;   // 98
    k_scan1<<<nsb, 512, 0, stream>>>(counts, row_ptr, partials, NN + 1);
    k_scan3<<<nsb, 512, 0, stream>>>(row_ptr, partials, NN + 1, nsb);
    k_fill<<<(NE + 255) / 256, 256, 0, stream>>>(esrc, edst, dist, row_ptr, srcd);

    const int ngb = (NN + 63) / 64;   // 782
    const int nab = (NN + 3) / 4;     // 12500

    for (int l = 0; l < NLAYER; ++l) {
        const unsigned short* wt = Wt12 + (size_t)l * 4 * 16384;
        if (l == 0) {
            k_gqkvs<<<ngb, 512, 0, stream>>>(x, NN, Wbt, bbe, wt,
                bq, bk, bv, bs, qb, kv8, hsb);
        } else {
            k_qkvs<<<ngb, 512, 0, stream>>>(hb, NN, wt,
                bq + l * HID, bk + l * HID, bv + l * HID, bs + l * HID,
                qb, kv8, hsb);
        }
        if (l < NLAYER - 1) {
            k_attn<0><<<nab, 256, 0, stream>>>(qb, hsb, kv8, srcd, We + l * HID,
                row_ptr, lng + l * HID, lnb + l * HID, hb, nullptr, nullptr, nullptr, NN);
        } else {
            k_attn<1><<<nab, 256, 0, stream>>>(qb, hsb, kv8, srcd, We + l * HID,
                row_ptr, lng + l * HID, lnb + l * HID, hb, Wat, baf, out, NN);
        }
    }
}

// Round 13
// 341.669 us; speedup vs baseline: 1.0851x; 1.0851x over previous
//
#include <hip/hip_runtime.h>
#include <cstdint>
#include <cstddef>

#define NN 50000
#define NE 600000
#define FIN 64
#define HID 128
#define NCLS 10
#define NLAYER 3

// 0.25 (1/sqrt(16)) * log2(e)  -> softmax exp becomes a single exp2
#define QSCALE 0.36067376022224085f

typedef __bf16 bf16x8 __attribute__((ext_vector_type(8)));
typedef float f32x4 __attribute__((ext_vector_type(4)));
typedef float f32x2 __attribute__((ext_vector_type(2)));

__device__ __forceinline__ unsigned short f2bf(float f) {
    unsigned int u = __builtin_bit_cast(unsigned int, f);
    u += 0x7fffu + ((u >> 16) & 1u);
    return (unsigned short)(u >> 16);
}
__device__ __forceinline__ float bf2f(unsigned short s) {
    unsigned int u = ((unsigned int)s) << 16;
    return __builtin_bit_cast(float, u);
}

// ---------------------------------------------------------------- prep: weights + count
__global__ __launch_bounds__(256) void k_prep(
    const float* __restrict__ Wq, const float* __restrict__ Wk,
    const float* __restrict__ Wv, const float* __restrict__ Ws,
    const float* __restrict__ Wbe, const float* __restrict__ Waf,
    unsigned short* __restrict__ Wt12,
    unsigned short* __restrict__ Wbt,
    float* __restrict__ Wat,
    const int* __restrict__ edst, int* __restrict__ counts)
{
    int blk = blockIdx.x;
    int tid = threadIdx.x;
    if (blk < 768) {
        int m = blk >> 6;                 // 0..11
        int l = m >> 2, which = m & 3;
        const float* src;
        if (which == 0) src = Wq; else if (which == 1) src = Wk;
        else if (which == 2) src = Wv; else src = Ws;
        src += (size_t)l * HID * HID;
        int idx = (blk & 63) * 256 + tid; // 0..16383
        int c = idx >> 7, k = idx & 127;
        Wt12[(size_t)m * 16384 + (size_t)c * 128 + k] = f2bf(src[(size_t)k * 128 + c]);
    } else if (blk < 800) {
        int idx = (blk - 768) * 256 + tid;  // 0..8191
        int c = idx >> 6, k = idx & 63;
        Wbt[(size_t)c * 64 + k] = f2bf(Wbe[(size_t)k * 128 + c]);
    } else if (blk < 805) {
        int i = (blk - 800) * 256 + tid;    // 0..1279
        if (i < 1280) {
            int c = i >> 7, f = i & 127;
            Wat[i] = Waf[f * 10 + c];
        }
    } else {
        int e = (blk - 805) * 256 + tid;
        if (e < NE) atomicAdd(&counts[edst[e]], 1);
    }
}

// ---------------------------------------------------------------- CSR scan (3-kernel, proven)
__global__ __launch_bounds__(512) void k_scan1(const int* __restrict__ counts,
                                               int* __restrict__ row_ptr,
                                               int* __restrict__ partials, int n) {
    __shared__ int sm[512];
    int tid = threadIdx.x;
    int i = blockIdx.x * 512 + tid;
    int v = (i < n) ? counts[i] : 0;
    sm[tid] = v;
    __syncthreads();
    #pragma unroll
    for (int off = 1; off < 512; off <<= 1) {
        int t = (tid >= off) ? sm[tid - off] : 0;
        __syncthreads();
        sm[tid] += t;
        __syncthreads();
    }
    if (i < n) row_ptr[i] = sm[tid] - v;
    if (tid == 511) partials[blockIdx.x] = sm[511];
}

__global__ __launch_bounds__(128) void k_scan2(int* __restrict__ partials, int nb) {
    __shared__ int sm[128];
    int t = threadIdx.x;
    int v = (t < nb) ? partials[t] : 0;
    sm[t] = v;
    __syncthreads();
    #pragma unroll
    for (int off = 1; off < 128; off <<= 1) {
        int x = (t >= off) ? sm[t - off] : 0;
        __syncthreads();
        sm[t] += x;
        __syncthreads();
    }
    if (t < nb) partials[t] = sm[t] - v;   // exclusive
}

__global__ __launch_bounds__(512) void k_scan3(int* __restrict__ row_ptr,
                                               const int* __restrict__ partials, int n) {
    int i = blockIdx.x * 512 + threadIdx.x;
    if (i < n) row_ptr[i] += partials[blockIdx.x];
}

// fill: atomicAdd directly on row_ptr. Afterwards row_ptr[d] = orig_row_ptr[d+1],
// so consumers read beg = row_ptr[n-1] (row_ptr[-1] is a zeroed sentinel).
__global__ __launch_bounds__(256) void k_fill(const int* __restrict__ esrc,
                                              const int* __restrict__ edst,
                                              const float* __restrict__ dist,
                                              int* __restrict__ row_ptr,
                                              int2* __restrict__ srcd) {
    int e = blockIdx.x * 256 + threadIdx.x;
    if (e < NE) {
        int d = edst[e];
        int slot = atomicAdd(&row_ptr[d], 1);
        srcd[slot] = make_int2(esrc[e], __float_as_int(dist[e]));
    }
}

// ---------------------------------------------------------------- QKVS core
// kv8 row layout: 32 chunks of 8B, chunk c = [k(4c..4c+3) 4B | v(4c..4c+3) 4B] fp8.
__device__ __forceinline__ void qkvs_store(
    int m, int arow, int colb, f32x4 acc, float4 bb, int nrows,
    unsigned short* __restrict__ qb, unsigned char* __restrict__ kv8,
    unsigned short* __restrict__ hsb)
{
    if (arow >= nrows) return;
    float v0 = acc[0] + bb.x, v1 = acc[1] + bb.y;
    float v2 = acc[2] + bb.z, v3 = acc[3] + bb.w;
    if (m == 0) {
        ushort4 o;
        o.x = f2bf(v0 * QSCALE); o.y = f2bf(v1 * QSCALE);
        o.z = f2bf(v2 * QSCALE); o.w = f2bf(v3 * QSCALE);
        *(ushort4*)(qb + (size_t)arow * 128 + colb) = o;
    } else if (m == 1 || m == 2) {
        unsigned int pk = __builtin_amdgcn_cvt_pk_fp8_f32(v0, v1, 0, false);
        pk = __builtin_amdgcn_cvt_pk_fp8_f32(v2, v3, pk, true);
        *(unsigned int*)(kv8 + (size_t)arow * 256 + (colb >> 2) * 8 + (m == 2 ? 4 : 0)) = pk;
    } else {
        ushort4 o;
        o.x = f2bf(v0); o.y = f2bf(v1); o.z = f2bf(v2); o.w = f2bf(v3);
        *(ushort4*)(hsb + (size_t)arow * 128 + colb) = o;
    }
}

// ---------------------------------------------------------------- fused QKVS GEMM (layers 1,2)
__global__ __launch_bounds__(512) void k_qkvs(
    const unsigned short* __restrict__ Ab, int nrows,
    const unsigned short* __restrict__ Wt,   // [4][128col][128k]
    const float* __restrict__ bq, const float* __restrict__ bk,
    const float* __restrict__ bv, const float* __restrict__ bs,
    unsigned short* __restrict__ qb,
    unsigned char* __restrict__ kv8,
    unsigned short* __restrict__ hsb)
{
    const int tid = threadIdx.x;
    const int w = tid >> 6, lane = tid & 63;
    const int m = w >> 1, ch = w & 1;
    const float* bias = (m == 0) ? bq : (m == 1) ? bk : (m == 2) ? bv : bs;
    const unsigned short* Wm = Wt + (size_t)m * 16384;
    const int lc = lane & 15, lk = lane >> 4;

    bf16x8 bw[4][4];
    float4 bb[4];
    #pragma unroll
    for (int ct = 0; ct < 4; ++ct) {
        int col = ch * 64 + ct * 16 + lc;
        bb[ct] = *(const float4*)(bias + ch * 64 + ct * 16 + lk * 4);
        #pragma unroll
        for (int kb = 0; kb < 4; ++kb)
            bw[ct][kb] = *(const bf16x8*)(Wm + (size_t)col * 128 + kb * 32 + lk * 8);
    }

    const int r0 = blockIdx.x * 64;
    #pragma unroll
    for (int rt = 0; rt < 4; ++rt) {
        const int arow = r0 + rt * 16 + lc;
        const bool rv = arow < nrows;
        bf16x8 z = {};
        bf16x8 a[4];
        #pragma unroll
        for (int kb = 0; kb < 4; ++kb)
            a[kb] = rv ? *(const bf16x8*)(Ab + (size_t)arow * 128 + kb * 32 + lk * 8) : z;
        #pragma unroll
        for (int ct = 0; ct < 4; ++ct) {
            f32x4 acc = {0.f, 0.f, 0.f, 0.f};
            #pragma unroll
            for (int kb = 0; kb < 4; ++kb)
                acc = __builtin_amdgcn_mfma_f32_16x16x32_bf16(bw[ct][kb], a[kb], acc, 0, 0, 0);
            qkvs_store(m, arow, ch * 64 + ct * 16 + lk * 4, acc, bb[ct], nrows, qb, kv8, hsb);
        }
    }
}

// ---------------------------------------------------------------- fused fc_before + layer0 QKVS
__global__ __launch_bounds__(512) void k_gqkvs(
    const float* __restrict__ x, int nrows,
    const unsigned short* __restrict__ Wbt,  // [128col][64k]
    const float* __restrict__ bbe,
    const unsigned short* __restrict__ Wt,   // layer0 [4][128col][128k]
    const float* __restrict__ bq, const float* __restrict__ bk,
    const float* __restrict__ bv, const float* __restrict__ bs,
    unsigned short* __restrict__ qb,
    unsigned char* __restrict__ kv8,
    unsigned short* __restrict__ hsb)
{
    __shared__ unsigned short hs_s[64 * 136];   // stride 136 shorts (272B) -> 2-way only
    const int tid = threadIdx.x;
    const int w = tid >> 6, lane = tid & 63;
    const int lc = lane & 15, lk = lane >> 4;
    const int r0 = blockIdx.x * 64;

    // ---- phase 1: wave w -> row-tile (w&3), col-half (w>>2)
    {
        const int rt0 = w & 3, ch0 = w >> 2;
        const int arl = rt0 * 16 + lc;
        const int arow = r0 + arl;
        const bool rv = arow < nrows;
        bf16x8 a[2];
        #pragma unroll
        for (int kb = 0; kb < 2; ++kb) {
            union { bf16x8 v; unsigned short u[8]; } t;
            #pragma unroll
            for (int q = 0; q < 2; ++q) {
                float4 f = rv ? *(const float4*)(x + (size_t)arow * 64 + kb * 32 + lk * 8 + q * 4)
                              : make_float4(0.f, 0.f, 0.f, 0.f);
                t.u[q * 4 + 0] = f2bf(f.x); t.u[q * 4 + 1] = f2bf(f.y);
                t.u[q * 4 + 2] = f2bf(f.z); t.u[q * 4 + 3] = f2bf(f.w);
            }
            a[kb] = t.v;
        }
        #pragma unroll
        for (int ct = 0; ct < 4; ++ct) {
            const int col = ch0 * 64 + ct * 16 + lc;
            f32x4 acc = {0.f, 0.f, 0.f, 0.f};
            #pragma unroll
            for (int kb = 0; kb < 2; ++kb) {
                bf16x8 bwf = *(const bf16x8*)(Wbt + (size_t)col * 64 + kb * 32 + lk * 8);
                acc = __builtin_amdgcn_mfma_f32_16x16x32_bf16(bwf, a[kb], acc, 0, 0, 0);
            }
            float4 bv_ = *(const float4*)(bbe + ch0 * 64 + ct * 16 + lk * 4);
            ushort4 o;
            o.x = rv ? f2bf(fmaxf(acc[0] + bv_.x, 0.f)) : 0;
            o.y = rv ? f2bf(fmaxf(acc[1] + bv_.y, 0.f)) : 0;
            o.z = rv ? f2bf(fmaxf(acc[2] + bv_.z, 0.f)) : 0;
            o.w = rv ? f2bf(fmaxf(acc[3] + bv_.w, 0.f)) : 0;
            *(ushort4*)(hs_s + arl * 136 + ch0 * 64 + ct * 16 + lk * 4) = o;
        }
    }
    __syncthreads();

    // ---- phase 2: standard QKVS, A from LDS
    const int m = w >> 1, ch = w & 1;
    const float* bias = (m == 0) ? bq : (m == 1) ? bk : (m == 2) ? bv : bs;
    const unsigned short* Wm = Wt + (size_t)m * 16384;

    bf16x8 bw[4][4];
    float4 bb[4];
    #pragma unroll
    for (int ct = 0; ct < 4; ++ct) {
        int col = ch * 64 + ct * 16 + lc;
        bb[ct] = *(const float4*)(bias + ch * 64 + ct * 16 + lk * 4);
        #pragma unroll
        for (int kb = 0; kb < 4; ++kb)
            bw[ct][kb] = *(const bf16x8*)(Wm + (size_t)col * 128 + kb * 32 + lk * 8);
    }

    #pragma unroll
    for (int rt = 0; rt < 4; ++rt) {
        const int arl = rt * 16 + lc;
        const int arow = r0 + arl;
        bf16x8 a[4];
        #pragma unroll
        for (int kb = 0; kb < 4; ++kb)
            a[kb] = *(const bf16x8*)(hs_s + arl * 136 + kb * 32 + lk * 8);
        #pragma unroll
        for (int ct = 0; ct < 4; ++ct) {
            f32x4 acc = {0.f, 0.f, 0.f, 0.f};
            #pragma unroll
            for (int kb = 0; kb < 4; ++kb)
                acc = __builtin_amdgcn_mfma_f32_16x16x32_bf16(bw[ct][kb], a[kb], acc, 0, 0, 0);
            qkvs_store(m, arow, ch * 64 + ct * 16 + lk * 4, acc, bb[ct], nrows, qb, kv8, hsb);
        }
    }
}

// ---------------------------------------------------------------- fused attention (r8 proven version)
// One wave per dst node. lane = (half = lane>>5 edge parity, l5 = lane&31
// owning dims 4*l5..4*l5+3). Edge list (<=64) loaded in ONE coalesced wave
// load; per chunk of 16 edges: 8 kv gathers burst-issued, then 8 computes.
// row_ptr here is the post-fill array: beg = row_ptr[n-1], end = row_ptr[n].
#define FET(Ki, i) {                                                      \
    int e_ = base + 2 * (i) + half;                                       \
    int ec_ = e_ < cmax ? e_ : 0;                                         \
    int sx_ = __shfl(sd0.x, ec_);                                         \
    Ki = *(const uint2*)(kv8 + (size_t)sx_ * 256 + l5 * 8); }

#define CMP(Ki, i) {                                                      \
    int e_ = base + 2 * (i) + half;                                       \
    bool val_ = e_ < cmax;                                                \
    int ec_ = val_ ? e_ : 0;                                              \
    float dd_ = __int_as_float(__shfl(sd0.y, ec_));                       \
    f32x2 k01_ = __builtin_amdgcn_cvt_pk_f32_fp8(Ki.x, false);            \
    f32x2 k23_ = __builtin_amdgcn_cvt_pk_f32_fp8(Ki.x, true);             \
    float p_ = q0 * k01_.x + q1 * k01_.y + q2 * k23_.x + q3 * k23_.y;     \
    p_ += __shfl_xor(p_, 1);                                              \
    p_ += __shfl_xor(p_, 2);                                              \
    p_ = fmaf(dd_, qwe, p_);                                              \
    float w_ = val_ ? exp2f(p_) : 0.f;                                    \
    s += w_;                                                              \
    sd = fmaf(dd_, w_, sd);                                               \
    f32x2 v01_ = __builtin_amdgcn_cvt_pk_f32_fp8(Ki.y, false);            \
    f32x2 v23_ = __builtin_amdgcn_cvt_pk_f32_fp8(Ki.y, true);             \
    va0 = fmaf(v01_.x, w_, va0); va1 = fmaf(v01_.y, w_, va1);             \
    va2 = fmaf(v23_.x, w_, va2); va3 = fmaf(v23_.y, w_, va3); }

template <int LAST>
__global__ __launch_bounds__(256, 6) void k_attn(
    const unsigned short* __restrict__ qb,
    const unsigned short* __restrict__ hsb,
    const unsigned char* __restrict__ kv8,
    const int2* __restrict__ srcd,
    const float* __restrict__ We,
    const int* __restrict__ row_ptr,
    const float* __restrict__ lng,
    const float* __restrict__ lnb,
    unsigned short* __restrict__ hb,
    const float* __restrict__ Wat,     // [10][128] (LAST)
    const float* __restrict__ ba,      // [10]      (LAST)
    float* __restrict__ out, int nnodes)
{
    const int wid = threadIdx.x >> 6;
    const int lane = threadIdx.x & 63;
    const int n = blockIdx.x * 4 + wid;
    if (n >= nnodes) return;
    const int half = lane >> 5;
    const int l5 = lane & 31;
    const int d0 = l5 * 4;

    const int beg = row_ptr[n - 1];    // sentinel row_ptr[-1] == 0
    const int cnt = row_ptr[n] - beg;

    // q slice (4 dims, pre-scaled bf16) + We slice
    ushort4 qu = *(const ushort4*)(qb + (size_t)n * 128 + d0);
    const float q0 = bf2f(qu.x), q1 = bf2f(qu.y), q2 = bf2f(qu.z), q3 = bf2f(qu.w);
    const float4 wv = *(const float4*)(We + d0);
    float qwe = q0 * wv.x + q1 * wv.y + q2 * wv.z + q3 * wv.w;
    qwe += __shfl_xor(qwe, 1);
    qwe += __shfl_xor(qwe, 2);

    float s = 0.f, sd = 0.f;
    float va0 = 0.f, va1 = 0.f, va2 = 0.f, va3 = 0.f;

    if (cnt > 0) {
        // whole edge list (<=64) in one coalesced wave load
        int2 sd0 = srcd[beg + (lane < cnt ? lane : 0)];
        const int cmax = cnt < 64 ? cnt : 64;
        const int nch = (cmax + 15) >> 4;
        for (int ch = 0; ch < nch; ++ch) {
            const int base = ch << 4;
            uint2 kA, kB, kC, kD, kE, kF, kG, kH;
            FET(kA, 0) FET(kB, 1) FET(kC, 2) FET(kD, 3)
            FET(kE, 4) FET(kF, 5) FET(kG, 6) FET(kH, 7)
            CMP(kA, 0) CMP(kB, 1) CMP(kC, 2) CMP(kD, 3)
            CMP(kE, 4) CMP(kF, 5) CMP(kG, 6) CMP(kH, 7)
        }
        // correctness tail for cnt > 64 (never taken on this graph)
        for (int e = 64 + half; e < cnt; e += 2) {
            int2 sde = srcd[beg + e];
            uint2 kr = *(const uint2*)(kv8 + (size_t)sde.x * 256 + l5 * 8);
            float dd_ = __int_as_float(sde.y);
            f32x2 k01_ = __builtin_amdgcn_cvt_pk_f32_fp8(kr.x, false);
            f32x2 k23_ = __builtin_amdgcn_cvt_pk_f32_fp8(kr.x, true);
            float p_ = q0 * k01_.x + q1 * k01_.y + q2 * k23_.x + q3 * k23_.y;
            p_ += __shfl_xor(p_, 1);
            p_ += __shfl_xor(p_, 2);
            p_ = fmaf(dd_, qwe, p_);
            float w_ = exp2f(p_);
            s += w_;
            sd = fmaf(dd_, w_, sd);
            f32x2 v01_ = __builtin_amdgcn_cvt_pk_f32_fp8(kr.y, false);
            f32x2 v23_ = __builtin_amdgcn_cvt_pk_f32_fp8(kr.y, true);
            va0 = fmaf(v01_.x, w_, va0); va1 = fmaf(v01_.y, w_, va1);
            va2 = fmaf(v23_.x, w_, va2); va3 = fmaf(v23_.y, w_, va3);
        }
    }

    // combine the two edge-parity halves
    s  += __shfl_xor(s, 32);
    sd += __shfl_xor(sd, 32);
    va0 += __shfl_xor(va0, 32);
    va1 += __shfl_xor(va1, 32);
    va2 += __shfl_xor(va2, 32);
    va3 += __shfl_xor(va3, 32);

    const float inv = 1.f / (s + 1e-16f);
    const ushort4 hu = *(const ushort4*)(hsb + (size_t)n * 128 + d0);
    float o0 = fmaf(fmaf(wv.x, sd, va0), inv, bf2f(hu.x));
    float o1 = fmaf(fmaf(wv.y, sd, va1), inv, bf2f(hu.y));
    float o2 = fmaf(fmaf(wv.z, sd, va2), inv, bf2f(hu.z));
    float o3 = fmaf(fmaf(wv.w, sd, va3), inv, bf2f(hu.w));

    // LayerNorm over 128 dims (4 per lane, duplicated across halves) + ReLU
    float tt = o0 + o1 + o2 + o3;
    #pragma unroll
    for (int msk = 1; msk < 32; msk <<= 1) tt += __shfl_xor(tt, msk);
    const float mean = tt * 0.0078125f;
    const float e0 = o0 - mean, e1 = o1 - mean, e2 = o2 - mean, e3 = o3 - mean;
    float vv2 = e0 * e0 + e1 * e1 + e2 * e2 + e3 * e3;
    #pragma unroll
    for (int msk = 1; msk < 32; msk <<= 1) vv2 += __shfl_xor(vv2, msk);
    const float rstd = rsqrtf(vv2 * 0.0078125f + 1e-5f);
    const float4 g4 = *(const float4*)(lng + d0);
    const float4 b4 = *(const float4*)(lnb + d0);
    const float y0 = fmaxf(fmaf(e0 * rstd, g4.x, b4.x), 0.f);
    const float y1 = fmaxf(fmaf(e1 * rstd, g4.y, b4.y), 0.f);
    const float y2 = fmaxf(fmaf(e2 * rstd, g4.z, b4.z), 0.f);
    const float y3 = fmaxf(fmaf(e3 * rstd, g4.w, b4.w), 0.f);

    if (LAST) {
        float lg[NCLS];
        #pragma unroll
        for (int c = 0; c < NCLS; ++c) {
            float4 wa = *(const float4*)(Wat + c * 128 + d0);
            float p = y0 * wa.x + y1 * wa.y + y2 * wa.z + y3 * wa.w;
            #pragma unroll
            for (int msk = 1; msk < 32; msk <<= 1) p += __shfl_xor(p, msk);
            lg[c] = p + ba[c];
        }
        float mx = lg[0];
        #pragma unroll
        for (int c = 1; c < NCLS; ++c) mx = fmaxf(mx, lg[c]);
        float sum = 0.f;
        #pragma unroll
        for (int c = 0; c < NCLS; ++c) sum += __expf(lg[c] - mx);
        float lse = mx + __logf(sum);
        if (lane == 0) {
            #pragma unroll
            for (int c = 0; c < NCLS; ++c) out[(size_t)n * NCLS + c] = lg[c] - lse;
        }
    } else if (lane < 32) {
        ushort4 o;
        o.x = f2bf(y0); o.y = f2bf(y1); o.z = f2bf(y2); o.w = f2bf(y3);
        *(ushort4*)(hb + (size_t)n * 128 + d0) = o;
    }
}

// ---------------------------------------------------------------- launch
extern "C" void kernel_launch(void* const* d_in, const int* in_sizes, int n_in,
                              void* d_out, int out_size, void* d_ws, size_t ws_size,
                              hipStream_t stream)
{
    const float* x    = (const float*)d_in[0];
    const int*   ei   = (const int*)d_in[1];
    const float* dist = (const float*)d_in[2];
    const float* Wq   = (const float*)d_in[3];
    const float* bq   = (const float*)d_in[4];
    const float* Wk   = (const float*)d_in[5];
    const float* bk   = (const float*)d_in[6];
    const float* Wv   = (const float*)d_in[7];
    const float* bv   = (const float*)d_in[8];
    const float* We   = (const float*)d_in[9];
    const float* Wsk  = (const float*)d_in[10];
    const float* bs   = (const float*)d_in[11];
    const float* lng  = (const float*)d_in[12];
    const float* lnb  = (const float*)d_in[13];
    const float* Wbe  = (const float*)d_in[14];
    const float* bbe  = (const float*)d_in[15];
    const float* Waf  = (const float*)d_in[16];
    const float* baf  = (const float*)d_in[17];
    float* out = (float*)d_out;
    const int* esrc = ei;
    const int* edst = ei + NE;

    char* ws = (char*)d_ws;
    size_t off = 0;
    unsigned short* qb  = (unsigned short*)(ws + off); off += 12800000;
    unsigned short* hsb = (unsigned short*)(ws + off); off += 12800000;
    unsigned char*  kv8 = (unsigned char*)(ws + off);  off += 12800000;
    unsigned short* hb  = (unsigned short*)(ws + off); off += 12800000;
    unsigned short* Wt12 = (unsigned short*)(ws + off); off += 393216;
    unsigned short* Wbt  = (unsigned short*)(ws + off); off += 16384;
    float* Wat = (float*)(ws + off);   off += 5120;
    int* counts   = (int*)(ws + off);  off += 200192;   // NN+1 used
    int* row_base = (int*)(ws + off);  off += 200704;   // [0]=sentinel 0, then NN+1 entries
    int* partials = (int*)(ws + off);  off += 512;
    int2* srcd    = (int2*)(ws + off); off += (size_t)NE * 8 + 4096;  // +guard
    int* row_ptr = row_base + 1;

    // zero counts + row_base sentinel in ONE memset (adjacent regions)
    hipMemsetAsync(counts, 0, 200192 + 4, stream);
    // weight prep + dst histogram
    k_prep<<<805 + (NE + 255) / 256, 256, 0, stream>>>(
        Wq, Wk, Wv, Wsk, Wbe, Waf, Wt12, Wbt, Wat, edst, counts);
    int nsb = (NN + 1 + 511) / 512;   // 98
    k_scan1<<<nsb, 512, 0, stream>>>(counts, row_ptr, partials, NN + 1);
    k_scan2<<<1, 128, 0, stream>>>(partials, nsb);
    k_scan3<<<nsb, 512, 0, stream>>>(row_ptr, partials, NN + 1);
    k_fill<<<(NE + 255) / 256, 256, 0, stream>>>(esrc, edst, dist, row_ptr, srcd);

    const int ngb = (NN + 63) / 64;   // 782
    const int nab = (NN + 3) / 4;     // 12500

    for (int l = 0; l < NLAYER; ++l) {
        const unsigned short* wt = Wt12 + (size_t)l * 4 * 16384;
        if (l == 0) {
            k_gqkvs<<<ngb, 512, 0, stream>>>(x, NN, Wbt, bbe, wt,
                bq, bk, bv, bs, qb, kv8, hsb);
        } else {
            k_qkvs<<<ngb, 512, 0, stream>>>(hb, NN, wt,
                bq + l * HID, bk + l * HID, bv + l * HID, bs + l * HID,
                qb, kv8, hsb);
        }
        if (l < NLAYER - 1) {
            k_attn<0><<<nab, 256, 0, stream>>>(qb, hsb, kv8, srcd, We + l * HID,
                row_ptr, lng + l * HID, lnb + l * HID, hb, nullptr, nullptr, nullptr, NN);
        } else {
            k_attn<1><<<nab, 256, 0, stream>>>(qb, hsb, kv8, srcd, We + l * HID,
                row_ptr, lng + l * HID, lnb + l * HID, hb, Wat, baf, out, NN);
        }
    }
}